// Round 1
// baseline (1308.176 us; speedup 1.0000x reference)
//
#include <hip/hip_runtime.h>
#include <hip/hip_bf16.h>
#include <math.h>

// Problem constants (fixed by the reference)
#define B_ROWS 16384
#define D_DIM  4096
#define H_DIM  2048
#define E_DIM  64
#define TEMP   0.8f

typedef __bf16 bf16x8 __attribute__((ext_vector_type(8)));
typedef float  f32x4  __attribute__((ext_vector_type(4)));
typedef unsigned short ushort8 __attribute__((ext_vector_type(8)));

__device__ __forceinline__ unsigned short bf_rne(float f) {
  unsigned u = __float_as_uint(f);
  u += 0x7FFF + ((u >> 16) & 1);
  return (unsigned short)(u >> 16);
}

__device__ __forceinline__ void async_copy16(const void* g, void* l) {
  __builtin_amdgcn_global_load_lds(
      (const __attribute__((address_space(1))) void*)g,
      (__attribute__((address_space(3))) void*)l, 16, 0, 0);
}

// ---------------------------------------------------------------------------
// split: fp32 -> (hi bf16, lo bf16), RNE both. 8 elements / thread.
// Used for W1, W2, and (fast path) x.
// ---------------------------------------------------------------------------
__global__ __launch_bounds__(256) void split_kernel(
    const float* __restrict__ in, unsigned short* __restrict__ hi,
    unsigned short* __restrict__ lo) {
  const size_t i = ((size_t)blockIdx.x * 256 + threadIdx.x) * 8;
  float4 v0 = *(const float4*)(in + i);
  float4 v1 = *(const float4*)(in + i + 4);
  float f[8] = {v0.x, v0.y, v0.z, v0.w, v1.x, v1.y, v1.z, v1.w};
  ushort8 hv, lv;
#pragma unroll
  for (int j = 0; j < 8; ++j) {
    unsigned short h = bf_rne(f[j]);
    float fh = __uint_as_float(((unsigned)h) << 16);
    hv[j] = h;
    lv[j] = bf_rne(f[j] - fh);
  }
  *(ushort8*)(hi + i) = hv;
  *(ushort8*)(lo + i) = lv;
}

// ---------------------------------------------------------------------------
// K1 v2: h = relu(x @ W1^T + b1), bf16x3 MFMA fp32 emulation.
// ALL staging via global_load_lds (pre-split xh/xl, w1h/w1l).
// LDS sources pre-swizzled so fragment ds_read_b128 is ~conflict-free:
//   content rule: LDS[row*32 + c] = logical(row, c ^ s1(row)),
//   s1(row) = ((row>>1)&3)<<3  (XOR is an involution; dest stays linear).
// Epilogue writes h split hi/lo bf16 (bit-identical to fp32-then-split).
// ---------------------------------------------------------------------------
#define BM 128
#define BN 128
#define BKK 32

__global__ __launch_bounds__(256) void gemm1_async_kernel(
    const unsigned short* __restrict__ xh, const unsigned short* __restrict__ xl,
    const unsigned short* __restrict__ w1h, const unsigned short* __restrict__ w1l,
    const float* __restrict__ b1,
    unsigned short* __restrict__ hhp, unsigned short* __restrict__ hlp) {
  __shared__ unsigned short Ah[BM * BKK];  // 8 KB each
  __shared__ unsigned short Al[BM * BKK];
  __shared__ unsigned short Bh[BN * BKK];
  __shared__ unsigned short Bl[BN * BKK];

  const int t    = threadIdx.x;
  const int lane = t & 63;
  const int w    = t >> 6;          // wave 0..3
  const int wm   = w >> 1;
  const int wn   = w & 1;
  const int m0   = blockIdx.y * BM;
  const int n0   = blockIdx.x * BN;

  // Staging: 2 chunks/thread per buffer. chunk = c*4+w writes LDS[chunk*512 + lane*8].
  // row = chunk*16 + (lane>>2); col = ((lane&3)*8) ^ s1(row)  (pre-swizzled source)
  const unsigned short* sAh[2];
  const unsigned short* sAl[2];
  const unsigned short* sBh[2];
  const unsigned short* sBl[2];
  unsigned short* dAh[2];
  unsigned short* dAl[2];
  unsigned short* dBh[2];
  unsigned short* dBl[2];
#pragma unroll
  for (int c = 0; c < 2; ++c) {
    const int chunk = c * 4 + w;
    const int row   = chunk * 16 + (lane >> 2);
    const int col   = ((lane & 3) * 8) ^ (((row >> 1) & 3) << 3);
    const int p     = chunk * 512 + lane * 8;
    sAh[c] = xh  + (size_t)(m0 + row) * D_DIM + col;
    sAl[c] = xl  + (size_t)(m0 + row) * D_DIM + col;
    sBh[c] = w1h + (size_t)(n0 + row) * D_DIM + col;
    sBl[c] = w1l + (size_t)(n0 + row) * D_DIM + col;
    dAh[c] = &Ah[p];
    dAl[c] = &Al[p];
    dBh[c] = &Bh[p];
    dBl[c] = &Bl[p];
  }

  // Fragment read addresses (swizzled to match)
  const int koff = (lane >> 4) * 8;
  const unsigned short* a_rd[4];
  const unsigned short* b_rd[4];
#pragma unroll
  for (int f = 0; f < 4; ++f) {
    const int Ra = wm * 64 + f * 16 + (lane & 15);
    const int ca = koff ^ (((Ra >> 1) & 3) << 3);
    a_rd[f] = &Ah[Ra * BKK + ca];
    const int Rb = wn * 64 + f * 16 + (lane & 15);
    const int cb = koff ^ (((Rb >> 1) & 3) << 3);
    b_rd[f] = &Bh[Rb * BKK + cb];
  }
  const int lo_off_a = (int)(Al - Ah);
  const int lo_off_b = (int)(Bl - Bh);

  f32x4 acc[4][4];
#pragma unroll
  for (int i = 0; i < 4; ++i)
#pragma unroll
    for (int j = 0; j < 4; ++j) acc[i][j] = (f32x4)0.f;

  for (int k0 = 0; k0 < D_DIM; k0 += BKK) {
#pragma unroll
    for (int c = 0; c < 2; ++c) {
      async_copy16(sAh[c] + k0, dAh[c]);
      async_copy16(sAl[c] + k0, dAl[c]);
      async_copy16(sBh[c] + k0, dBh[c]);
      async_copy16(sBl[c] + k0, dBl[c]);
    }
    __syncthreads();

    bf16x8 fa_h[4], fa_l[4], fb_h[4], fb_l[4];
#pragma unroll
    for (int ff = 0; ff < 4; ++ff) {
      fa_h[ff] = *(const bf16x8*)(a_rd[ff]);
      fa_l[ff] = *(const bf16x8*)(a_rd[ff] + lo_off_a);
      fb_h[ff] = *(const bf16x8*)(b_rd[ff]);
      fb_l[ff] = *(const bf16x8*)(b_rd[ff] + lo_off_b);
    }
#pragma unroll
    for (int i = 0; i < 4; ++i)
#pragma unroll
      for (int j = 0; j < 4; ++j) {
        acc[i][j] = __builtin_amdgcn_mfma_f32_16x16x32_bf16(fa_h[i], fb_h[j], acc[i][j], 0, 0, 0);
        acc[i][j] = __builtin_amdgcn_mfma_f32_16x16x32_bf16(fa_l[i], fb_h[j], acc[i][j], 0, 0, 0);
        acc[i][j] = __builtin_amdgcn_mfma_f32_16x16x32_bf16(fa_h[i], fb_l[j], acc[i][j], 0, 0, 0);
      }
    __syncthreads();
  }

  // Epilogue: bias + relu, write h as hi/lo bf16 (same bytes as fp32).
  // C layout: col=lane&15, row=(lane>>4)*4+reg
#pragma unroll
  for (int fn = 0; fn < 4; ++fn) {
    const int n = n0 + wn * 64 + fn * 16 + (lane & 15);
    const float bias = b1[n];
#pragma unroll
    for (int fm = 0; fm < 4; ++fm) {
      const int mbase = m0 + wm * 64 + fm * 16 + (lane >> 4) * 4;
#pragma unroll
      for (int r = 0; r < 4; ++r) {
        const float vv = fmaxf(acc[fm][fn][r] + bias, 0.f);
        const unsigned short hv = bf_rne(vv);
        const float fh = __uint_as_float(((unsigned)hv) << 16);
        const unsigned short lv = bf_rne(vv - fh);
        hhp[(size_t)(mbase + r) * H_DIM + n] = hv;
        hlp[(size_t)(mbase + r) * H_DIM + n] = lv;
      }
    }
  }
}

// ---------------------------------------------------------------------------
// K1 fallback (workspace too small for xh/xl): in-kernel x split, identical to
// the proven previous kernel except the epilogue writes split h.
// ---------------------------------------------------------------------------
__global__ __launch_bounds__(256) void gemm1_fb_kernel(
    const float* __restrict__ x,
    const unsigned short* __restrict__ w1h,
    const unsigned short* __restrict__ w1l,
    const float* __restrict__ b1,
    unsigned short* __restrict__ hhp, unsigned short* __restrict__ hlp) {
  __shared__ unsigned short Ah[BM * BKK];
  __shared__ unsigned short Al[BM * BKK];
  __shared__ unsigned short Bh[BN * BKK];
  __shared__ unsigned short Bl[BN * BKK];

  const int t    = threadIdx.x;
  const int lane = t & 63;
  const int w    = t >> 6;
  const int wm   = w >> 1;
  const int wn   = w & 1;
  const int m0   = blockIdx.y * BM;
  const int n0   = blockIdx.x * BN;

  const int e0 = (w * 2 + 0) * 512 + lane * 8;
  const int e1 = (w * 2 + 1) * 512 + lane * 8;
  const int r0 = e0 >> 5, c0 = e0 & 31;
  const int r1 = e1 >> 5, c1 = e1 & 31;
  const unsigned short* bh_g0 = w1h + (size_t)(n0 + r0) * D_DIM + c0;
  const unsigned short* bh_g1 = w1h + (size_t)(n0 + r1) * D_DIM + c1;
  const unsigned short* bl_g0 = w1l + (size_t)(n0 + r0) * D_DIM + c0;
  const unsigned short* bl_g1 = w1l + (size_t)(n0 + r1) * D_DIM + c1;
  unsigned short* bh_l0 = &Bh[e0];
  unsigned short* bh_l1 = &Bh[e1];
  unsigned short* bl_l0 = &Bl[e0];
  unsigned short* bl_l1 = &Bl[e1];

  const int ar = t >> 1;
  const int ac = (t & 1) * 16;
  const float* xp = x + (size_t)(m0 + ar) * D_DIM + ac;
  unsigned short* ah_w = &Ah[ar * BKK + ac];
  unsigned short* al_w = &Al[ar * BKK + ac];

  const int koff = (lane >> 4) * 8;
  const unsigned short* a_rd[4];
  const unsigned short* b_rd[4];
#pragma unroll
  for (int f = 0; f < 4; ++f) {
    a_rd[f] = &Ah[(wm * 64 + f * 16 + (lane & 15)) * BKK + koff];
    b_rd[f] = &Bh[(wn * 64 + f * 16 + (lane & 15)) * BKK + koff];
  }
  const int lo_off_a = (int)(Al - Ah);
  const int lo_off_b = (int)(Bl - Bh);

  f32x4 acc[4][4];
#pragma unroll
  for (int i = 0; i < 4; ++i)
#pragma unroll
    for (int j = 0; j < 4; ++j) acc[i][j] = (f32x4)0.f;

  for (int k0 = 0; k0 < D_DIM; k0 += BKK) {
    async_copy16(bh_g0 + k0, bh_l0);
    async_copy16(bh_g1 + k0, bh_l1);
    async_copy16(bl_g0 + k0, bl_l0);
    async_copy16(bl_g1 + k0, bl_l1);

    float4 v[4];
#pragma unroll
    for (int j = 0; j < 4; ++j) v[j] = *(const float4*)(xp + k0 + j * 4);
    float f[16] = {v[0].x, v[0].y, v[0].z, v[0].w, v[1].x, v[1].y, v[1].z, v[1].w,
                   v[2].x, v[2].y, v[2].z, v[2].w, v[3].x, v[3].y, v[3].z, v[3].w};
    ushort8 hv0, hv1, lv0, lv1;
#pragma unroll
    for (int j = 0; j < 8; ++j) {
      unsigned short h = bf_rne(f[j]);
      float fh = __uint_as_float(((unsigned)h) << 16);
      hv0[j] = h;
      lv0[j] = bf_rne(f[j] - fh);
    }
#pragma unroll
    for (int j = 0; j < 8; ++j) {
      unsigned short h = bf_rne(f[8 + j]);
      float fh = __uint_as_float(((unsigned)h) << 16);
      hv1[j] = h;
      lv1[j] = bf_rne(f[8 + j] - fh);
    }
    *(ushort8*)(ah_w)     = hv0;
    *(ushort8*)(ah_w + 8) = hv1;
    *(ushort8*)(al_w)     = lv0;
    *(ushort8*)(al_w + 8) = lv1;

    __syncthreads();

    bf16x8 fa_h[4], fa_l[4], fb_h[4], fb_l[4];
#pragma unroll
    for (int ff = 0; ff < 4; ++ff) {
      fa_h[ff] = *(const bf16x8*)(a_rd[ff]);
      fa_l[ff] = *(const bf16x8*)(a_rd[ff] + lo_off_a);
      fb_h[ff] = *(const bf16x8*)(b_rd[ff]);
      fb_l[ff] = *(const bf16x8*)(b_rd[ff] + lo_off_b);
    }
#pragma unroll
    for (int i = 0; i < 4; ++i)
#pragma unroll
      for (int j = 0; j < 4; ++j) {
        acc[i][j] = __builtin_amdgcn_mfma_f32_16x16x32_bf16(fa_h[i], fb_h[j], acc[i][j], 0, 0, 0);
        acc[i][j] = __builtin_amdgcn_mfma_f32_16x16x32_bf16(fa_l[i], fb_h[j], acc[i][j], 0, 0, 0);
        acc[i][j] = __builtin_amdgcn_mfma_f32_16x16x32_bf16(fa_h[i], fb_l[j], acc[i][j], 0, 0, 0);
      }
    __syncthreads();
  }

#pragma unroll
  for (int fn = 0; fn < 4; ++fn) {
    const int n = n0 + wn * 64 + fn * 16 + (lane & 15);
    const float bias = b1[n];
#pragma unroll
    for (int fm = 0; fm < 4; ++fm) {
      const int mbase = m0 + wm * 64 + fm * 16 + (lane >> 4) * 4;
#pragma unroll
      for (int r = 0; r < 4; ++r) {
        const float vv = fmaxf(acc[fm][fn][r] + bias, 0.f);
        const unsigned short hv = bf_rne(vv);
        const float fh = __uint_as_float(((unsigned)hv) << 16);
        const unsigned short lv = bf_rne(vv - fh);
        hhp[(size_t)(mbase + r) * H_DIM + n] = hv;
        hlp[(size_t)(mbase + r) * H_DIM + n] = lv;
      }
    }
  }
}

// ---------------------------------------------------------------------------
// K2 fused: logits = h @ W2^T + b2 (bf16x3) -> top-2 + softmax + entropy.
// h now pre-split hi/lo bf16 -> ALL staging via global_load_lds, BK=64
// (halves the latency-exposed iteration count). Same swizzle discipline:
//   LDS[row*64 + c] = logical(row, c ^ s2(row)), s2(row) = (row&7)<<3.
// ---------------------------------------------------------------------------
#define F_BM 64
#define F_BK 64

__global__ __launch_bounds__(256) void gemm2_router_kernel(
    const unsigned short* __restrict__ hhp,
    const unsigned short* __restrict__ hlp,
    const unsigned short* __restrict__ w2h,
    const unsigned short* __restrict__ w2l,
    const float* __restrict__ b2,
    float* __restrict__ out, float* __restrict__ accum) {
  __shared__ unsigned short Ah[F_BM * F_BK];   // 8 KB each
  __shared__ unsigned short Al[F_BM * F_BK];
  __shared__ unsigned short Bh[E_DIM * F_BK];
  __shared__ unsigned short Bl[E_DIM * F_BK];
  __shared__ float LG[F_BM][E_DIM + 1];        // +1 pad: kills col conflicts

  const int t    = threadIdx.x;
  const int lane = t & 63;
  const int w    = t >> 6;
  const int m0   = blockIdx.x * F_BM;

  // Staging: 2 chunks/thread per buffer, tile [64 rows][64 k].
  // chunk = c*4+w; row = chunk*8 + (lane>>3); col = ((lane&7)*8) ^ s2(row)
  const unsigned short* sAh[2];
  const unsigned short* sAl[2];
  const unsigned short* sBh[2];
  const unsigned short* sBl[2];
  unsigned short* dAh[2];
  unsigned short* dAl[2];
  unsigned short* dBh[2];
  unsigned short* dBl[2];
#pragma unroll
  for (int c = 0; c < 2; ++c) {
    const int chunk = c * 4 + w;
    const int row   = chunk * 8 + (lane >> 3);
    const int col   = ((lane & 7) * 8) ^ ((row & 7) << 3);
    const int p     = chunk * 512 + lane * 8;
    sAh[c] = hhp + (size_t)(m0 + row) * H_DIM + col;
    sAl[c] = hlp + (size_t)(m0 + row) * H_DIM + col;
    sBh[c] = w2h + (size_t)row * H_DIM + col;   // row == expert index
    sBl[c] = w2l + (size_t)row * H_DIM + col;
    dAh[c] = &Ah[p];
    dAl[c] = &Al[p];
    dBh[c] = &Bh[p];
    dBl[c] = &Bl[p];
  }

  // Fragment reads: wave w owns rows w*16..w*16+15 x all 64 experts.
  const int koff = (lane >> 4) * 8;
  const int Ra = w * 16 + (lane & 15);
  const unsigned short* a_rd[2];
  const unsigned short* b_rd[2][4];
#pragma unroll
  for (int kk = 0; kk < 2; ++kk) {
    const int ca = (kk * 32 + koff) ^ ((Ra & 7) << 3);
    a_rd[kk] = &Ah[Ra * F_BK + ca];
#pragma unroll
    for (int f = 0; f < 4; ++f) {
      const int Rb = f * 16 + (lane & 15);
      const int cb = (kk * 32 + koff) ^ ((Rb & 7) << 3);
      b_rd[kk][f] = &Bh[Rb * F_BK + cb];
    }
  }
  const int lo_off_a = (int)(Al - Ah);
  const int lo_off_b = (int)(Bl - Bh);

  f32x4 acc[4];
#pragma unroll
  for (int f = 0; f < 4; ++f) acc[f] = (f32x4)0.f;

  for (int k0 = 0; k0 < H_DIM; k0 += F_BK) {
#pragma unroll
    for (int c = 0; c < 2; ++c) {
      async_copy16(sAh[c] + k0, dAh[c]);
      async_copy16(sAl[c] + k0, dAl[c]);
      async_copy16(sBh[c] + k0, dBh[c]);
      async_copy16(sBl[c] + k0, dBl[c]);
    }
    __syncthreads();

#pragma unroll
    for (int kk = 0; kk < 2; ++kk) {
      bf16x8 fa_h = *(const bf16x8*)(a_rd[kk]);
      bf16x8 fa_l = *(const bf16x8*)(a_rd[kk] + lo_off_a);
#pragma unroll
      for (int f = 0; f < 4; ++f) {
        bf16x8 fb_h = *(const bf16x8*)(b_rd[kk][f]);
        bf16x8 fb_l = *(const bf16x8*)(b_rd[kk][f] + lo_off_b);
        acc[f] = __builtin_amdgcn_mfma_f32_16x16x32_bf16(fa_h, fb_h, acc[f], 0, 0, 0);
        acc[f] = __builtin_amdgcn_mfma_f32_16x16x32_bf16(fa_l, fb_h, acc[f], 0, 0, 0);
        acc[f] = __builtin_amdgcn_mfma_f32_16x16x32_bf16(fa_h, fb_l, acc[f], 0, 0, 0);
      }
    }
    __syncthreads();
  }

  // Epilogue: bias, stash logits tile in LDS.
#pragma unroll
  for (int f = 0; f < 4; ++f) {
    const int e = f * 16 + (lane & 15);
    const float bias = b2[e];
#pragma unroll
    for (int r = 0; r < 4; ++r) {
      const int ml = w * 16 + (lane >> 4) * 4 + r;
      LG[ml][e] = acc[f][r] + bias;
    }
  }
  __syncthreads();

  // Router: threads 0..63 each own one row.
  if (t < F_BM) {
    const int row = m0 + t;
    float l0 = LG[t][0]; int i0 = 0;
    float l1 = -INFINITY; int i1 = -1;
#pragma unroll
    for (int e = 1; e < E_DIM; ++e) {
      float v = LG[t][e];
      if (v > l0)      { l1 = l0; i1 = i0; l0 = v; i0 = e; }
      else if (v > l1) { l1 = v; i1 = e; }
    }

    const float eT = expf((l1 - l0) / TEMP);
    const float w0 = 1.f / (1.f + eT);
    const float w1 = eT / (1.f + eT);

    float Z = 0.f;
#pragma unroll
    for (int e = 0; e < E_DIM; ++e) Z += expf(LG[t][e] - l0);
    const float invZ = 1.f / Z;
    float ent = 0.f;
#pragma unroll
    for (int e = 0; e < E_DIM; ++e) {
      float p = expf(LG[t][e] - l0) * invZ;
      ent -= p * logf(p + 1e-10f);
    }

    out[(size_t)row * 2 + 0] = w0;
    out[(size_t)row * 2 + 1] = w1;
    out[(size_t)B_ROWS * 2 + (size_t)row * 2 + 0] = (float)i0;
    out[(size_t)B_ROWS * 2 + (size_t)row * 2 + 1] = (float)i1;

#pragma unroll
    for (int off = 32; off > 0; off >>= 1) ent += __shfl_down(ent, off);
    if (t == 0) atomicAdd(accum, ent);
  }
}

__global__ void zero_kernel(float* p) { p[0] = 0.f; }

__global__ void finalize_kernel(const float* __restrict__ accum,
                                float* __restrict__ out) {
  out[(size_t)B_ROWS * 4] = accum[0] / ((float)B_ROWS * logf((float)E_DIM));
}

// ---------------------------------------------------------------------------
extern "C" void kernel_launch(void* const* d_in, const int* in_sizes, int n_in,
                              void* d_out, int out_size, void* d_ws,
                              size_t ws_size, hipStream_t stream) {
  const float* x  = (const float*)d_in[0];
  const float* W1 = (const float*)d_in[1];
  const float* b1 = (const float*)d_in[2];
  const float* W2 = (const float*)d_in[3];
  const float* b2 = (const float*)d_in[4];
  float* out = (float*)d_out;

  const size_t SZ_W1 = (size_t)H_DIM * D_DIM;   // 8,388,608
  const size_t SZ_W2 = (size_t)E_DIM * H_DIM;   // 131,072
  const size_t SZ_H  = (size_t)B_ROWS * H_DIM;  // 33,554,432
  const size_t SZ_X  = (size_t)B_ROWS * D_DIM;  // 67,108,864

  // ws layout (fallback-safe prefix first, xh/xl optional tail):
  unsigned short* w1h = (unsigned short*)d_ws;
  unsigned short* w1l = w1h + SZ_W1;
  unsigned short* w2h = w1l + SZ_W1;
  unsigned short* w2l = w2h + SZ_W2;
  unsigned short* hhp = w2l + SZ_W2;
  unsigned short* hlp = hhp + SZ_H;
  float* accum        = (float*)(hlp + SZ_H);
  unsigned short* xh  = (unsigned short*)(accum + 64);  // keep 16B alignment
  unsigned short* xl  = xh + SZ_X;
  const size_t need_bytes = (size_t)((char*)(xl + SZ_X) - (char*)d_ws);
  const bool fast = ws_size >= need_bytes;

  zero_kernel<<<1, 1, 0, stream>>>(accum);

  split_kernel<<<(int)(SZ_W1 / (256 * 8)), 256, 0, stream>>>(W1, w1h, w1l);
  split_kernel<<<(int)(SZ_W2 / (256 * 8)), 256, 0, stream>>>(W2, w2h, w2l);

  dim3 g1(H_DIM / BN, B_ROWS / BM);  // (16, 128)
  if (fast) {
    split_kernel<<<(int)(SZ_X / (256 * 8)), 256, 0, stream>>>(x, xh, xl);
    gemm1_async_kernel<<<g1, 256, 0, stream>>>(xh, xl, w1h, w1l, b1, hhp, hlp);
  } else {
    gemm1_fb_kernel<<<g1, 256, 0, stream>>>(x, w1h, w1l, b1, hhp, hlp);
  }

  gemm2_router_kernel<<<B_ROWS / F_BM, 256, 0, stream>>>(hhp, hlp, w2h, w2l, b2,
                                                         out, accum);

  finalize_kernel<<<1, 1, 0, stream>>>(accum, out);
}